// Round 13
// baseline (480.171 us; speedup 1.0000x reference)
//
#include <hip/hip_runtime.h>
#include <hip/hip_bf16.h>
#include <math.h>

typedef __attribute__((ext_vector_type(8))) short bf16x8;
typedef __attribute__((ext_vector_type(4))) float f32x4;
typedef unsigned short u16;

#define NHEAD 12

__device__ __forceinline__ u16 f2bf(float f) {
  __hip_bfloat16 h = __float2bfloat16(f);
  return __builtin_bit_cast(u16, h);
}

__device__ __forceinline__ void gload16(const void* g, void* l) {
  __builtin_amdgcn_global_load_lds(
      (const __attribute__((address_space(1))) void*)g,
      (__attribute__((address_space(3))) void*)l, 16, 0, 0);
}

// ---------------- all weights fp32 -> bf16, packed dst ----------------
__global__ void cvt_all(const float* __restrict__ s0, const float* __restrict__ s1,
                        const float* __restrict__ s2, const float* __restrict__ s3,
                        u16* __restrict__ d) {
  int i = blockIdx.x * 256 + threadIdx.x;  // total 1769472
  if (i >= 1769472) return;
  float v;
  if (i < 442368) v = s0[i];
  else if (i < 589824) v = s1[i - 442368];
  else if (i < 1179648) v = s2[i - 589824];
  else v = s3[i - 1179648];
  d[i] = f2bf(v);
}

// ---------------- relative-position bias table [12][64][64] ----------------
__global__ void build_bias(const float* __restrict__ rpb, float* __restrict__ bt) {
  int i = blockIdx.x * 256 + threadIdx.x;
  if (i >= NHEAD * 4096) return;
  int h = i >> 12;
  int q = (i >> 6) & 63;
  int k = i & 63;
  int qi = q >> 3, qj = q & 7, ki = k >> 3, kj = k & 7;
  int idx = (qi - ki + 7) * 15 + (qj - kj + 7);
  bt[i] = rpb[idx * NHEAD + h];
}

// ---------------- LayerNorm: fp32 in -> bf16 out, C=384, 1 wave/row ----------------
// float2 loads: 3 x dwordx2 per lane (cols lane*2 + {0,1} + i*128), coalesced.
__global__ __launch_bounds__(256) void ln_k(const float* __restrict__ x,
                                            const float* __restrict__ g,
                                            const float* __restrict__ b,
                                            u16* __restrict__ out) {
  int row = (blockIdx.x << 2) + (threadIdx.x >> 6);
  int lane = threadIdx.x & 63;
  const float* xr = x + (size_t)row * 384;
  float2 v[3];
  float s = 0.f;
#pragma unroll
  for (int i = 0; i < 3; ++i) {
    v[i] = *(const float2*)&xr[(lane << 1) + (i << 7)];
    s += v[i].x + v[i].y;
  }
#pragma unroll
  for (int o = 32; o; o >>= 1) s += __shfl_xor(s, o, 64);
  float mu = s * (1.f / 384.f);
  float vs = 0.f;
#pragma unroll
  for (int i = 0; i < 3; ++i) {
    float dx = v[i].x - mu, dy = v[i].y - mu;
    vs += dx * dx + dy * dy;
  }
#pragma unroll
  for (int o = 32; o; o >>= 1) vs += __shfl_xor(vs, o, 64);
  float rs = rsqrtf(vs * (1.f / 384.f) + 1e-5f);
  u16* orow = out + (size_t)row * 384;
#pragma unroll
  for (int i = 0; i < 3; ++i) {
    int c = (lane << 1) + (i << 7);
    orow[c] = f2bf((v[i].x - mu) * rs * g[c] + b[c]);
    orow[c + 1] = f2bf((v[i].y - mu) * rs * g[c + 1] + b[c + 1]);
  }
}

// ---------------- m97-style GEMM (best measured config) ----------------
// out[M,N] = A[M,K](bf16) @ W[N,K]^T(bf16) + bias, epilogues:
// EP 0: +bias -> bf16 (QKV)   EP 1: +bias+res -> fp32 (proj)
// EP 2: +bias gelu -> bf16 (FC1)   EP 3: +bias+res -> fp32 (FC2)
// 128x128 tile, BK=64, 256 threads = 4 waves (2x2), single 32KB LDS buffer,
// 2 barriers per K-step; 4 blocks/CU staggered phases hide the drain.
// XOR swizzle: row r, 16B slot s holds global col-block s^(r&7); read at
// slot (kk*4 + (lane>>4)) ^ (r&7)  -> 2-way max (free).
template <int EP>
__global__ __launch_bounds__(256, 4) void gemmA(const u16* __restrict__ A,
                                                const u16* __restrict__ W,
                                                const float* __restrict__ bias,
                                                const float* __restrict__ res,
                                                void* __restrict__ outp,
                                                int N, int K, int nCol) {
  __shared__ u16 As[128 * 64];
  __shared__ u16 Bs[128 * 64];
  const int tid = threadIdx.x;
  const int wave = tid >> 6, lane = tid & 63;
  const int wm = wave >> 1, wn = wave & 1;
  const int nwg = gridDim.x, cpx = nwg >> 3;
  const int lin = (blockIdx.x & 7) * cpx + (blockIdx.x >> 3);
  const int rowT = lin / nCol;
  const int colT = lin - rowT * nCol;
  const int rowBase = rowT << 7;
  const int colBase = colT << 7;
  const int nK = K >> 6;

  const int g16 = (tid & 7) ^ ((tid >> 3) & 7);
  const u16* Asrc = A + (size_t)(rowBase + (tid >> 3)) * K + (g16 << 3);
  const u16* Wsrc = W + (size_t)(colBase + (tid >> 3)) * K + (g16 << 3);
  const int ldst = tid << 3;

  const int q4 = lane >> 4;
  const int rx = lane & 7;
  const int arow = (wm << 6) + (lane & 15);
  const int brow = (wn << 6) + (lane & 15);

  f32x4 acc[4][4] = {};

  for (int j = 0; j < nK; ++j) {
    const size_t k0 = (size_t)j << 6;
#pragma unroll
    for (int c = 0; c < 4; ++c) {
      gload16(Asrc + (size_t)(c << 5) * K + k0, &As[(c << 11) + ldst]);
      gload16(Wsrc + (size_t)(c << 5) * K + k0, &Bs[(c << 11) + ldst]);
    }
    __syncthreads();
#pragma unroll
    for (int kk = 0; kk < 2; ++kk) {
      const int slot = (((kk << 2) + q4) ^ rx) << 3;
      bf16x8 aF[4], bF[4];
#pragma unroll
      for (int m = 0; m < 4; ++m)
        aF[m] = *(const bf16x8*)&As[(arow + (m << 4)) * 64 + slot];
#pragma unroll
      for (int n = 0; n < 4; ++n)
        bF[n] = *(const bf16x8*)&Bs[(brow + (n << 4)) * 64 + slot];
#pragma unroll
      for (int m = 0; m < 4; ++m)
#pragma unroll
        for (int n = 0; n < 4; ++n)
          acc[m][n] = __builtin_amdgcn_mfma_f32_16x16x32_bf16(aF[m], bF[n], acc[m][n], 0, 0, 0);
    }
    __syncthreads();
  }

#pragma unroll
  for (int m = 0; m < 4; ++m) {
#pragma unroll
    for (int n = 0; n < 4; ++n) {
      const int col = colBase + (wn << 6) + (n << 4) + (lane & 15);
      const int row0 = rowBase + (wm << 6) + (m << 4) + ((lane >> 4) << 2);
      const float bv = bias[col];
#pragma unroll
      for (int jj = 0; jj < 4; ++jj) {
        const size_t row = (size_t)(row0 + jj);
        float y = acc[m][n][jj] + bv;
        if (EP == 0) {
          ((u16*)outp)[row * N + col] = f2bf(y);
        } else if (EP == 1) {
          ((float*)outp)[row * N + col] = y + res[row * N + col];
        } else if (EP == 2) {
          // gelu = y * sigmoid(2u); exact algebraic rewrite of the tanh form
          float y2 = y * y;
          float t = __builtin_fmaf(y2, 0.1029434f, 2.3022118f);
          float e = __builtin_amdgcn_exp2f(-(y * t));
          y = y * __builtin_amdgcn_rcpf(1.f + e);
          ((u16*)outp)[row * N + col] = f2bf(y);
        } else {
          ((float*)outp)[row * N + col] = y + res[row * N + col];
        }
      }
    }
  }
}

// ---------------- window attention: one block per (window, head) ----------------
// XCD swizzle: 12 consecutive logical ids (= the 12 heads of one window) land
// in one XCD chunk so they share the window's qkv rows in that XCD's L2.
__global__ __launch_bounds__(256) void attn_k(const u16* __restrict__ qkv,
                                              const float* __restrict__ bias_tab,
                                              u16* __restrict__ o) {
  const int cpx = gridDim.x >> 3;
  const int lin = (blockIdx.x & 7) * cpx + (blockIdx.x >> 3);
  const int w = lin / NHEAD;
  const int h = lin - w * NHEAD;
  const int tid = threadIdx.x, wave = tid >> 6, lane = tid & 63;
  __shared__ u16 q_s[64 * 32];
  __shared__ u16 k_s[64 * 32];
  __shared__ u16 vt_s[32 * 64];
  __shared__ u16 p_s[4][16 * 72];
  const int b = w >> 6;
  const int wim = w & 63;
  const int wr0 = (wim >> 3) << 3, wc0 = (wim & 7) << 3;
  {
    const int r = tid >> 2, d0 = (tid & 3) << 3;
    const int pr = r >> 3, pc = r & 7;
    const int orow = (wr0 + pr + 4) & 63, ocol = (wc0 + pc + 4) & 63;
    const size_t t = ((size_t)b << 12) + (orow << 6) + ocol;
    const u16* base = qkv + t * 1152 + h * 32 + d0;
    *(uint4*)&q_s[r * 32 + d0] = *(const uint4*)(base);
    *(uint4*)&k_s[r * 32 + d0] = *(const uint4*)(base + 384);
    u16 vv[8];
    *(uint4*)vv = *(const uint4*)(base + 768);
#pragma unroll
    for (int j = 0; j < 8; ++j) vt_s[(d0 + j) * 64 + r] = vv[j];
  }
  __syncthreads();
  const int cIdx = lane & 15, rgrp = lane >> 4;
  const f32x4 zz = {0.f, 0.f, 0.f, 0.f};
  bf16x8 qa = *(const bf16x8*)&q_s[((wave << 4) + cIdx) * 32 + (rgrp << 3)];
  f32x4 s_acc[4];
#pragma unroll
  for (int n = 0; n < 4; ++n) {
    bf16x8 kb = *(const bf16x8*)&k_s[((n << 4) + cIdx) * 32 + (rgrp << 3)];
    s_acc[n] = __builtin_amdgcn_mfma_f32_16x16x32_bf16(qa, kb, zz, 0, 0, 0);
  }
  const float scale = 0.1767766952966369f;
  float mrow[4] = {-1e30f, -1e30f, -1e30f, -1e30f};
  const float* bt = bias_tab + h * 4096 + ((wave << 4) + (rgrp << 2)) * 64 + cIdx;
#pragma unroll
  for (int n = 0; n < 4; ++n)
#pragma unroll
    for (int j = 0; j < 4; ++j) {
      float val = s_acc[n][j] * scale + bt[j * 64 + (n << 4)];
      s_acc[n][j] = val;
      mrow[j] = fmaxf(mrow[j], val);
    }
#pragma unroll
  for (int j = 0; j < 4; ++j)
#pragma unroll
    for (int o2 = 1; o2 < 16; o2 <<= 1) mrow[j] = fmaxf(mrow[j], __shfl_xor(mrow[j], o2, 64));
  float srow[4] = {0.f, 0.f, 0.f, 0.f};
#pragma unroll
  for (int n = 0; n < 4; ++n)
#pragma unroll
    for (int j = 0; j < 4; ++j) {
      float e = __expf(s_acc[n][j] - mrow[j]);
      s_acc[n][j] = e;
      srow[j] += e;
    }
#pragma unroll
  for (int j = 0; j < 4; ++j)
#pragma unroll
    for (int o2 = 1; o2 < 16; o2 <<= 1) srow[j] += __shfl_xor(srow[j], o2, 64);
  float rinv[4];
#pragma unroll
  for (int j = 0; j < 4; ++j) rinv[j] = 1.f / srow[j];
  u16* pw = p_s[wave];
#pragma unroll
  for (int n = 0; n < 4; ++n)
#pragma unroll
    for (int j = 0; j < 4; ++j)
      pw[((rgrp << 2) + j) * 72 + (n << 4) + cIdx] = f2bf(s_acc[n][j] * rinv[j]);
  f32x4 o_acc[2] = {};
#pragma unroll
  for (int kk = 0; kk < 2; ++kk) {
    bf16x8 pa = *(const bf16x8*)&pw[cIdx * 72 + (kk << 5) + (rgrp << 3)];
#pragma unroll
    for (int c2 = 0; c2 < 2; ++c2) {
      bf16x8 vb = *(const bf16x8*)&vt_s[((c2 << 4) + cIdx) * 64 + (kk << 5) + (rgrp << 3)];
      o_acc[c2] = __builtin_amdgcn_mfma_f32_16x16x32_bf16(pa, vb, o_acc[c2], 0, 0, 0);
    }
  }
#pragma unroll
  for (int c2 = 0; c2 < 2; ++c2)
#pragma unroll
    for (int j = 0; j < 4; ++j) {
      const int p = (wave << 4) + (rgrp << 2) + j;
      const int pr = p >> 3, pc = p & 7;
      const int orow = (wr0 + pr + 4) & 63, ocol = (wc0 + pc + 4) & 63;
      const size_t t = ((size_t)b << 12) + (orow << 6) + ocol;
      o[t * 384 + h * 32 + (c2 << 4) + cIdx] = f2bf(o_acc[c2][j]);
    }
}

extern "C" void kernel_launch(void* const* d_in, const int* in_sizes, int n_in,
                              void* d_out, int out_size, void* d_ws, size_t ws_size,
                              hipStream_t stream) {
  const float* x = (const float*)d_in[0];
  const float* n1g = (const float*)d_in[1];
  const float* n1b = (const float*)d_in[2];
  const float* qkv_w = (const float*)d_in[3];
  const float* qkv_b = (const float*)d_in[4];
  const float* proj_w = (const float*)d_in[5];
  const float* proj_b = (const float*)d_in[6];
  const float* rpb = (const float*)d_in[7];
  const float* n2g = (const float*)d_in[8];
  const float* n2b = (const float*)d_in[9];
  const float* fc1_w = (const float*)d_in[10];
  const float* fc1_b = (const float*)d_in[11];
  const float* fc2_w = (const float*)d_in[12];
  const float* fc2_b = (const float*)d_in[13];

  char* ws = (char*)d_ws;
  u16* wqkv = (u16*)(ws + 0);                // 442368 elems
  u16* wproj = (u16*)(ws + 884736);          // 147456
  u16* wfc1 = (u16*)(ws + 1179648);          // 589824
  u16* wfc2 = (u16*)(ws + 2359296);          // 589824
  float* bias_tab = (float*)(ws + 3538944);
  u16* qkv = (u16*)(ws + 3735552);           // region A (qkv, then m1)
  u16* m1 = qkv;
  u16* hbuf = (u16*)(ws + 205062144);        // region B (h -> o -> h2)
  u16* obuf = hbuf;
  float* x1 = (float*)d_out;                 // x1 lives in d_out

  cvt_all<<<(1769472 + 255) / 256, 256, 0, stream>>>(qkv_w, proj_w, fc1_w, fc2_w, wqkv);
  build_bias<<<192, 256, 0, stream>>>(rpb, bias_tab);

  ln_k<<<16384, 256, 0, stream>>>(x, n1g, n1b, hbuf);
  gemmA<0><<<4608, 256, 0, stream>>>(hbuf, wqkv, qkv_b, nullptr, qkv, 1152, 384, 9);
  attn_k<<<12288, 256, 0, stream>>>(qkv, bias_tab, obuf);
  gemmA<1><<<1536, 256, 0, stream>>>(obuf, wproj, proj_b, x, x1, 384, 384, 3);
  ln_k<<<16384, 256, 0, stream>>>(x1, n2g, n2b, hbuf);
  gemmA<2><<<6144, 256, 0, stream>>>(hbuf, wfc1, fc1_b, nullptr, m1, 1536, 384, 12);
  gemmA<3><<<1536, 256, 0, stream>>>(m1, wfc2, fc2_b, x1, (float*)d_out, 384, 1536, 3);
}

// Round 14
// 476.635 us; speedup vs baseline: 1.0074x; 1.0074x over previous
//
#include <hip/hip_runtime.h>
#include <hip/hip_bf16.h>
#include <math.h>

typedef __attribute__((ext_vector_type(8))) short bf16x8;
typedef __attribute__((ext_vector_type(4))) float f32x4;
typedef unsigned short u16;

#define NHEAD 12

__device__ __forceinline__ u16 f2bf(float f) {
  __hip_bfloat16 h = __float2bfloat16(f);
  return __builtin_bit_cast(u16, h);
}

__device__ __forceinline__ void gload16(const void* g, void* l) {
  __builtin_amdgcn_global_load_lds(
      (const __attribute__((address_space(1))) void*)g,
      (__attribute__((address_space(3))) void*)l, 16, 0, 0);
}

// ---------------- all weights fp32 -> bf16, packed dst ----------------
__global__ void cvt_all(const float* __restrict__ s0, const float* __restrict__ s1,
                        const float* __restrict__ s2, const float* __restrict__ s3,
                        u16* __restrict__ d) {
  int i = blockIdx.x * 256 + threadIdx.x;  // total 1769472
  if (i >= 1769472) return;
  float v;
  if (i < 442368) v = s0[i];
  else if (i < 589824) v = s1[i - 442368];
  else if (i < 1179648) v = s2[i - 589824];
  else v = s3[i - 1179648];
  d[i] = f2bf(v);
}

// ---------------- relative-position bias table [12][64][64] ----------------
__global__ void build_bias(const float* __restrict__ rpb, float* __restrict__ bt) {
  int i = blockIdx.x * 256 + threadIdx.x;
  if (i >= NHEAD * 4096) return;
  int h = i >> 12;
  int q = (i >> 6) & 63;
  int k = i & 63;
  int qi = q >> 3, qj = q & 7, ki = k >> 3, kj = k & 7;
  int idx = (qi - ki + 7) * 15 + (qj - kj + 7);
  bt[i] = rpb[idx * NHEAD + h];
}

// ---------------- LayerNorm: fp32 in -> bf16 out, C=384, 1 wave/row ----------------
__global__ __launch_bounds__(256) void ln_k(const float* __restrict__ x,
                                            const float* __restrict__ g,
                                            const float* __restrict__ b,
                                            u16* __restrict__ out) {
  int row = (blockIdx.x << 2) + (threadIdx.x >> 6);
  int lane = threadIdx.x & 63;
  const float* xr = x + (size_t)row * 384;
  float v[6];
  float s = 0.f;
#pragma unroll
  for (int i = 0; i < 6; ++i) { v[i] = xr[lane + (i << 6)]; s += v[i]; }
#pragma unroll
  for (int o = 32; o; o >>= 1) s += __shfl_xor(s, o, 64);
  float mu = s * (1.f / 384.f);
  float vs = 0.f;
#pragma unroll
  for (int i = 0; i < 6; ++i) { float d0 = v[i] - mu; vs += d0 * d0; }
#pragma unroll
  for (int o = 32; o; o >>= 1) vs += __shfl_xor(vs, o, 64);
  float rs = rsqrtf(vs * (1.f / 384.f) + 1e-5f);
  u16* orow = out + (size_t)row * 384;
#pragma unroll
  for (int i = 0; i < 6; ++i) {
    int c = lane + (i << 6);
    orow[c] = f2bf((v[i] - mu) * rs * g[c] + b[c]);
  }
}

// ---------------- m97-style GEMM (best measured config) ----------------
// out[M,N] = A[M,K](bf16) @ W[N,K]^T(bf16) + bias, epilogues:
// EP 0: +bias -> bf16 (QKV)   EP 1: +bias+res -> fp32 (proj)
// EP 2: +bias gelu -> bf16 (FC1)   EP 3: +bias+res -> fp32 (FC2)
// 128x128 tile, BK=64, 256 threads = 4 waves (2x2), single 32KB LDS buffer,
// 2 barriers per K-step; 4 blocks/CU staggered phases hide the drain.
// XOR swizzle: row r, 16B slot s holds global col-block s^(r&7); read at
// slot (kk*4 + (lane>>4)) ^ (r&7)  -> 2-way max (free).
template <int EP>
__global__ __launch_bounds__(256, 4) void gemmA(const u16* __restrict__ A,
                                                const u16* __restrict__ W,
                                                const float* __restrict__ bias,
                                                const float* __restrict__ res,
                                                void* __restrict__ outp,
                                                int N, int K, int nCol) {
  __shared__ u16 As[128 * 64];
  __shared__ u16 Bs[128 * 64];
  const int tid = threadIdx.x;
  const int wave = tid >> 6, lane = tid & 63;
  const int wm = wave >> 1, wn = wave & 1;
  const int nwg = gridDim.x, cpx = nwg >> 3;
  const int lin = (blockIdx.x & 7) * cpx + (blockIdx.x >> 3);
  const int rowT = lin / nCol;
  const int colT = lin - rowT * nCol;
  const int rowBase = rowT << 7;
  const int colBase = colT << 7;
  const int nK = K >> 6;

  const int g16 = (tid & 7) ^ ((tid >> 3) & 7);
  const u16* Asrc = A + (size_t)(rowBase + (tid >> 3)) * K + (g16 << 3);
  const u16* Wsrc = W + (size_t)(colBase + (tid >> 3)) * K + (g16 << 3);
  const int ldst = tid << 3;

  const int q4 = lane >> 4;
  const int rx = lane & 7;
  const int arow = (wm << 6) + (lane & 15);
  const int brow = (wn << 6) + (lane & 15);

  f32x4 acc[4][4] = {};

  for (int j = 0; j < nK; ++j) {
    const size_t k0 = (size_t)j << 6;
#pragma unroll
    for (int c = 0; c < 4; ++c) {
      gload16(Asrc + (size_t)(c << 5) * K + k0, &As[(c << 11) + ldst]);
      gload16(Wsrc + (size_t)(c << 5) * K + k0, &Bs[(c << 11) + ldst]);
    }
    __syncthreads();
#pragma unroll
    for (int kk = 0; kk < 2; ++kk) {
      const int slot = (((kk << 2) + q4) ^ rx) << 3;
      bf16x8 aF[4], bF[4];
#pragma unroll
      for (int m = 0; m < 4; ++m)
        aF[m] = *(const bf16x8*)&As[(arow + (m << 4)) * 64 + slot];
#pragma unroll
      for (int n = 0; n < 4; ++n)
        bF[n] = *(const bf16x8*)&Bs[(brow + (n << 4)) * 64 + slot];
#pragma unroll
      for (int m = 0; m < 4; ++m)
#pragma unroll
        for (int n = 0; n < 4; ++n)
          acc[m][n] = __builtin_amdgcn_mfma_f32_16x16x32_bf16(aF[m], bF[n], acc[m][n], 0, 0, 0);
    }
    __syncthreads();
  }

#pragma unroll
  for (int m = 0; m < 4; ++m) {
#pragma unroll
    for (int n = 0; n < 4; ++n) {
      const int col = colBase + (wn << 6) + (n << 4) + (lane & 15);
      const int row0 = rowBase + (wm << 6) + (m << 4) + ((lane >> 4) << 2);
      const float bv = bias[col];
#pragma unroll
      for (int jj = 0; jj < 4; ++jj) {
        const size_t row = (size_t)(row0 + jj);
        float y = acc[m][n][jj] + bv;
        if (EP == 0) {
          ((u16*)outp)[row * N + col] = f2bf(y);
        } else if (EP == 1) {
          ((float*)outp)[row * N + col] = y + res[row * N + col];
        } else if (EP == 2) {
          // gelu = y * sigmoid(2u); exact algebraic rewrite of the tanh form
          float y2 = y * y;
          float t = __builtin_fmaf(y2, 0.1029434f, 2.3022118f);
          float e = __builtin_amdgcn_exp2f(-(y * t));
          y = y * __builtin_amdgcn_rcpf(1.f + e);
          ((u16*)outp)[row * N + col] = f2bf(y);
        } else {
          ((float*)outp)[row * N + col] = y + res[row * N + col];
        }
      }
    }
  }
}

// ---------------- window attention: one block per (window, head) ----------------
// XCD swizzle: 12 consecutive logical ids (= the 12 heads of one window) land
// in one XCD chunk so they share the window's qkv rows in that XCD's L2.
__global__ __launch_bounds__(256) void attn_k(const u16* __restrict__ qkv,
                                              const float* __restrict__ bias_tab,
                                              u16* __restrict__ o) {
  const int cpx = gridDim.x >> 3;
  const int lin = (blockIdx.x & 7) * cpx + (blockIdx.x >> 3);
  const int w = lin / NHEAD;
  const int h = lin - w * NHEAD;
  const int tid = threadIdx.x, wave = tid >> 6, lane = tid & 63;
  __shared__ u16 q_s[64 * 32];
  __shared__ u16 k_s[64 * 32];
  __shared__ u16 vt_s[32 * 64];
  __shared__ u16 p_s[4][16 * 72];
  const int b = w >> 6;
  const int wim = w & 63;
  const int wr0 = (wim >> 3) << 3, wc0 = (wim & 7) << 3;
  {
    const int r = tid >> 2, d0 = (tid & 3) << 3;
    const int pr = r >> 3, pc = r & 7;
    const int orow = (wr0 + pr + 4) & 63, ocol = (wc0 + pc + 4) & 63;
    const size_t t = ((size_t)b << 12) + (orow << 6) + ocol;
    const u16* base = qkv + t * 1152 + h * 32 + d0;
    *(uint4*)&q_s[r * 32 + d0] = *(const uint4*)(base);
    *(uint4*)&k_s[r * 32 + d0] = *(const uint4*)(base + 384);
    u16 vv[8];
    *(uint4*)vv = *(const uint4*)(base + 768);
#pragma unroll
    for (int j = 0; j < 8; ++j) vt_s[(d0 + j) * 64 + r] = vv[j];
  }
  __syncthreads();
  const int cIdx = lane & 15, rgrp = lane >> 4;
  const f32x4 zz = {0.f, 0.f, 0.f, 0.f};
  bf16x8 qa = *(const bf16x8*)&q_s[((wave << 4) + cIdx) * 32 + (rgrp << 3)];
  f32x4 s_acc[4];
#pragma unroll
  for (int n = 0; n < 4; ++n) {
    bf16x8 kb = *(const bf16x8*)&k_s[((n << 4) + cIdx) * 32 + (rgrp << 3)];
    s_acc[n] = __builtin_amdgcn_mfma_f32_16x16x32_bf16(qa, kb, zz, 0, 0, 0);
  }
  const float scale = 0.1767766952966369f;
  float mrow[4] = {-1e30f, -1e30f, -1e30f, -1e30f};
  const float* bt = bias_tab + h * 4096 + ((wave << 4) + (rgrp << 2)) * 64 + cIdx;
#pragma unroll
  for (int n = 0; n < 4; ++n)
#pragma unroll
    for (int j = 0; j < 4; ++j) {
      float val = s_acc[n][j] * scale + bt[j * 64 + (n << 4)];
      s_acc[n][j] = val;
      mrow[j] = fmaxf(mrow[j], val);
    }
#pragma unroll
  for (int j = 0; j < 4; ++j)
#pragma unroll
    for (int o2 = 1; o2 < 16; o2 <<= 1) mrow[j] = fmaxf(mrow[j], __shfl_xor(mrow[j], o2, 64));
  float srow[4] = {0.f, 0.f, 0.f, 0.f};
#pragma unroll
  for (int n = 0; n < 4; ++n)
#pragma unroll
    for (int j = 0; j < 4; ++j) {
      float e = __expf(s_acc[n][j] - mrow[j]);
      s_acc[n][j] = e;
      srow[j] += e;
    }
#pragma unroll
  for (int j = 0; j < 4; ++j)
#pragma unroll
    for (int o2 = 1; o2 < 16; o2 <<= 1) srow[j] += __shfl_xor(srow[j], o2, 64);
  float rinv[4];
#pragma unroll
  for (int j = 0; j < 4; ++j) rinv[j] = 1.f / srow[j];
  u16* pw = p_s[wave];
#pragma unroll
  for (int n = 0; n < 4; ++n)
#pragma unroll
    for (int j = 0; j < 4; ++j)
      pw[((rgrp << 2) + j) * 72 + (n << 4) + cIdx] = f2bf(s_acc[n][j] * rinv[j]);
  f32x4 o_acc[2] = {};
#pragma unroll
  for (int kk = 0; kk < 2; ++kk) {
    bf16x8 pa = *(const bf16x8*)&pw[cIdx * 72 + (kk << 5) + (rgrp << 3)];
#pragma unroll
    for (int c2 = 0; c2 < 2; ++c2) {
      bf16x8 vb = *(const bf16x8*)&vt_s[((c2 << 4) + cIdx) * 64 + (kk << 5) + (rgrp << 3)];
      o_acc[c2] = __builtin_amdgcn_mfma_f32_16x16x32_bf16(pa, vb, o_acc[c2], 0, 0, 0);
    }
  }
#pragma unroll
  for (int c2 = 0; c2 < 2; ++c2)
#pragma unroll
    for (int j = 0; j < 4; ++j) {
      const int p = (wave << 4) + (rgrp << 2) + j;
      const int pr = p >> 3, pc = p & 7;
      const int orow = (wr0 + pr + 4) & 63, ocol = (wc0 + pc + 4) & 63;
      const size_t t = ((size_t)b << 12) + (orow << 6) + ocol;
      o[t * 384 + h * 32 + (c2 << 4) + cIdx] = f2bf(o_acc[c2][j]);
    }
}

extern "C" void kernel_launch(void* const* d_in, const int* in_sizes, int n_in,
                              void* d_out, int out_size, void* d_ws, size_t ws_size,
                              hipStream_t stream) {
  const float* x = (const float*)d_in[0];
  const float* n1g = (const float*)d_in[1];
  const float* n1b = (const float*)d_in[2];
  const float* qkv_w = (const float*)d_in[3];
  const float* qkv_b = (const float*)d_in[4];
  const float* proj_w = (const float*)d_in[5];
  const float* proj_b = (const float*)d_in[6];
  const float* rpb = (const float*)d_in[7];
  const float* n2g = (const float*)d_in[8];
  const float* n2b = (const float*)d_in[9];
  const float* fc1_w = (const float*)d_in[10];
  const float* fc1_b = (const float*)d_in[11];
  const float* fc2_w = (const float*)d_in[12];
  const float* fc2_b = (const float*)d_in[13];

  char* ws = (char*)d_ws;
  u16* wqkv = (u16*)(ws + 0);                // 442368 elems
  u16* wproj = (u16*)(ws + 884736);          // 147456
  u16* wfc1 = (u16*)(ws + 1179648);          // 589824
  u16* wfc2 = (u16*)(ws + 2359296);          // 589824
  float* bias_tab = (float*)(ws + 3538944);
  u16* qkv = (u16*)(ws + 3735552);           // region A (qkv, then m1)
  u16* m1 = qkv;
  u16* hbuf = (u16*)(ws + 205062144);        // region B (h -> o -> h2)
  u16* obuf = hbuf;
  float* x1 = (float*)d_out;                 // x1 lives in d_out

  cvt_all<<<(1769472 + 255) / 256, 256, 0, stream>>>(qkv_w, proj_w, fc1_w, fc2_w, wqkv);
  build_bias<<<192, 256, 0, stream>>>(rpb, bias_tab);

  ln_k<<<16384, 256, 0, stream>>>(x, n1g, n1b, hbuf);
  gemmA<0><<<4608, 256, 0, stream>>>(hbuf, wqkv, qkv_b, nullptr, qkv, 1152, 384, 9);
  attn_k<<<12288, 256, 0, stream>>>(qkv, bias_tab, obuf);
  gemmA<1><<<1536, 256, 0, stream>>>(obuf, wproj, proj_b, x, x1, 384, 384, 3);
  ln_k<<<16384, 256, 0, stream>>>(x1, n2g, n2b, hbuf);
  gemmA<2><<<6144, 256, 0, stream>>>(hbuf, wfc1, fc1_b, nullptr, m1, 1536, 384, 12);
  gemmA<3><<<1536, 256, 0, stream>>>(m1, wfc2, fc2_b, x1, (float*)d_out, 384, 1536, 3);
}